// Round 3
// baseline (1765.298 us; speedup 1.0000x reference)
//
#include <hip/hip_runtime.h>
#include <hip/hip_bf16.h>
#include <cstdint>
#include <cstddef>

#define NPTS 4096
#define BATCH 16

// ---------------- generic 1x1-conv GEMM: out[b,o,n] = base(b,o) + sum_c wt[c,o]*act[b,c,n]
// wt is (C,O) fp32 (pre-transposed). 64x64 tile, K-tile 16, 4x4 micro-tile per thread.
__global__ __launch_bounds__(256) void conv_gemm(
    const float* __restrict__ act, const float* __restrict__ wt,
    const float* __restrict__ rowbias, const float* __restrict__ obias,
    float* __restrict__ out, int C, int O)
{
  __shared__ float As[16][68];
  __shared__ float Ws[16][68];
  const int b  = blockIdx.z;
  const int o0 = blockIdx.y * 64;
  const int n0 = blockIdx.x * 64;
  const int t  = threadIdx.x;
  const int tx = t & 15, ty = t >> 4;
  float acc[4][4] = {};
  const float* actb = act + ((size_t)b * C) * NPTS;

  for (int k0 = 0; k0 < C; k0 += 16) {
    const int r  = ty;         // k row within tile
    const int cs = tx * 4;     // column group
    const int k  = k0 + r;
    float4 av = make_float4(0.f, 0.f, 0.f, 0.f);
    if (k < C) av = *(const float4*)(actb + (size_t)k * NPTS + n0 + cs);
    *(float4*)&As[r][cs] = av;

    float4 wv = make_float4(0.f, 0.f, 0.f, 0.f);
    if (k < C) {
      const float* wp = wt + (size_t)k * O;
      const int o = o0 + cs;
      if (o + 3 < O) {
        wv = *(const float4*)&wp[o];
      } else {
        float tmp[4] = {0.f, 0.f, 0.f, 0.f};
        for (int j = 0; j < 4; ++j) if (o + j < O) tmp[j] = wp[o + j];
        wv = make_float4(tmp[0], tmp[1], tmp[2], tmp[3]);
      }
    }
    *(float4*)&Ws[r][cs] = wv;
    __syncthreads();

    const int kmax = (C - k0 < 16) ? (C - k0) : 16;
    for (int kk = 0; kk < kmax; ++kk) {
      float4 a = *(float4*)&As[kk][tx * 4];
      float4 w = *(float4*)&Ws[kk][ty * 4];
      acc[0][0] += w.x * a.x; acc[0][1] += w.x * a.y; acc[0][2] += w.x * a.z; acc[0][3] += w.x * a.w;
      acc[1][0] += w.y * a.x; acc[1][1] += w.y * a.y; acc[1][2] += w.y * a.z; acc[1][3] += w.y * a.w;
      acc[2][0] += w.z * a.x; acc[2][1] += w.z * a.y; acc[2][2] += w.z * a.z; acc[2][3] += w.z * a.w;
      acc[3][0] += w.w * a.x; acc[3][1] += w.w * a.y; acc[3][2] += w.w * a.z; acc[3][3] += w.w * a.w;
    }
    __syncthreads();
  }

  for (int i = 0; i < 4; ++i) {
    const int o = o0 + ty * 4 + i;
    if (o >= O) continue;
    float base = 0.f;
    if (rowbias) base  = rowbias[(size_t)b * O + o];
    if (obias)   base += obias[o];
    float4 v = make_float4(acc[i][0] + base, acc[i][1] + base, acc[i][2] + base, acc[i][3] + base);
    *(float4*)&out[((size_t)b * O + o) * NPTS + n0 + tx * 4] = v;
  }
}

// ---------------- BN (training mode): deterministic two-stage reduction
// stage 1: per-(b,c) partial sums (no atomics)
__global__ __launch_bounds__(256) void bn_reduce(const float* __restrict__ raw,
                                                 float* __restrict__ partials, int C) {
  const int c = blockIdx.x, b = blockIdx.y;
  const float* p = raw + ((size_t)b * C + c) * NPTS;
  float s = 0.f, s2 = 0.f;
  for (int i = threadIdx.x * 4; i < NPTS; i += 1024) {
    float4 v = *(const float4*)&p[i];
    s  += v.x + v.y + v.z + v.w;
    s2 += v.x * v.x + v.y * v.y + v.z * v.z + v.w * v.w;
  }
  for (int off = 32; off; off >>= 1) {
    s  += __shfl_down(s,  off, 64);
    s2 += __shfl_down(s2, off, 64);
  }
  __shared__ float ls[4], ls2[4];
  const int wid = threadIdx.x >> 6;
  if ((threadIdx.x & 63) == 0) { ls[wid] = s; ls2[wid] = s2; }
  __syncthreads();
  if (threadIdx.x == 0) {
    for (int k = 1; k < 4; ++k) { s += ls[k]; s2 += ls2[k]; }
    partials[(size_t)b * C + c] = s;
    partials[(size_t)BATCH * C + (size_t)b * C + c] = s2;
  }
}

// stage 2: fixed-order sum over batch partials
__global__ __launch_bounds__(256) void bn_finalize(const float* __restrict__ partials,
                                                   const float* __restrict__ g, const float* __restrict__ be,
                                                   float* __restrict__ scale, float* __restrict__ shift, int C) {
  int c = blockIdx.x * 256 + threadIdx.x;
  if (c >= C) return;
  float s = 0.f, s2 = 0.f;
  for (int b = 0; b < BATCH; ++b) {
    s  += partials[(size_t)b * C + c];
    s2 += partials[(size_t)BATCH * C + (size_t)b * C + c];
  }
  const float inv = 1.f / 65536.f;
  float m   = s * inv;
  float var = s2 * inv - m * m;
  float sc  = g[c] * rsqrtf(var + 1e-5f);
  scale[c] = sc;
  shift[c] = be[c] - m * sc;
}

__global__ __launch_bounds__(256) void bn_apply(float* __restrict__ data,
                                                const float* __restrict__ scale,
                                                const float* __restrict__ shift, int C, int relu) {
  size_t i4 = (size_t)blockIdx.x * 256 + threadIdx.x;
  size_t total4 = (size_t)BATCH * C * NPTS / 4;
  if (i4 >= total4) return;
  int c = (int)(((i4 * 4) >> 12) % (size_t)C);
  float sc = scale[c], sh = shift[c];
  float4 v = *(float4*)&data[i4 * 4];
  v.x = v.x * sc + sh; v.y = v.y * sc + sh; v.z = v.z * sc + sh; v.w = v.w * sc + sh;
  if (relu) {
    v.x = fmaxf(v.x, 0.f); v.y = fmaxf(v.y, 0.f);
    v.z = fmaxf(v.z, 0.f); v.w = fmaxf(v.w, 0.f);
  }
  *(float4*)&data[i4 * 4] = v;
}

// ---------------- top-32 per (b, sorting-channel), descending, lower index wins ties
__global__ __launch_bounds__(256) void topk_kernel(const float* __restrict__ h3,
                                                   int* __restrict__ idxp) {
  __shared__ float vals[NPTS];
  __shared__ float wv[4];
  __shared__ int   wi[4];
  const int c = blockIdx.x, b = blockIdx.y;
  const float* src = h3 + ((size_t)b * 256 + c) * NPTS;
  const int t = threadIdx.x;
  for (int i = t; i < NPTS; i += 256) vals[i] = src[i];
  __syncthreads();
  int* dst = idxp + ((size_t)b * 256 + c) * 32;
  for (int r = 0; r < 32; ++r) {
    float bv = -INFINITY; int bi = NPTS;
    for (int i = t; i < NPTS; i += 256) {
      float v = vals[i];
      if (v > bv || (v == bv && i < bi)) { bv = v; bi = i; }
    }
    for (int off = 32; off; off >>= 1) {
      float ov = __shfl_down(bv, off, 64);
      int   oi = __shfl_down(bi, off, 64);
      if (ov > bv || (ov == bv && oi < bi)) { bv = ov; bi = oi; }
    }
    const int wid = t >> 6;
    if ((t & 63) == 0) { wv[wid] = bv; wi[wid] = bi; }
    __syncthreads();
    if (t == 0) {
      for (int k = 1; k < 4; ++k)
        if (wv[k] > bv || (wv[k] == bv && wi[k] < bi)) { bv = wv[k]; bi = wi[k]; }
      dst[r] = bi;
      vals[bi] = -INFINITY;
    }
    __syncthreads();
  }
}

// ---------------- transpose h3 (B,C,N) -> h3T (B,N,C), C=256
__global__ __launch_bounds__(256) void transpose_h3(const float* __restrict__ h3,
                                                    float* __restrict__ h3T) {
  __shared__ float tile[32][33];
  const int b = blockIdx.z;
  const int n0 = blockIdx.x * 32, c0 = blockIdx.y * 32;
  const int tx = threadIdx.x & 31, ty = threadIdx.x >> 5;
  const float* src = h3 + (size_t)b * 256 * NPTS;
  for (int j = 0; j < 4; ++j)
    tile[ty + j * 8][tx] = src[(size_t)(c0 + ty + j * 8) * NPTS + n0 + tx];
  __syncthreads();
  float* dst = h3T + (size_t)b * NPTS * 256;
  for (int j = 0; j < 4; ++j)
    dst[(size_t)(n0 + ty + j * 8) * 256 + c0 + tx] = tile[tx][ty + j * 8];
}

// ---------------- transpose w8 (o,c,w) -> w8t (w,o,c)  [65536 x 256 2D transpose, fp32]
__global__ __launch_bounds__(256) void transpose_w8(const float* __restrict__ w8,
                                                    float* __restrict__ w8t) {
  __shared__ float tile[64][65];
  const int m0 = blockIdx.x * 64, w0 = blockIdx.y * 64;
  const int tx = threadIdx.x & 63, ty = threadIdx.x >> 6; // ty 0..3
  for (int j = 0; j < 16; ++j)
    tile[ty + j * 4][tx] = w8[(size_t)(m0 + ty + j * 4) * 256 + w0 + tx];
  __syncthreads();
  for (int j = 0; j < 16; ++j)
    w8t[(size_t)(w0 + ty + j * 4) * 65536 + m0 + tx] = tile[tx][ty + j * 4];
}

// ---------------- small weight transpose: dst(Csub,O) <- src(O,Ctot) cols [cOff, cOff+Csub)
__global__ __launch_bounds__(256) void transpose_w(const float* __restrict__ src,
                                                   float* __restrict__ dst,
                                                   int O, int Ctot, int cOff, int Csub) {
  int i = blockIdx.x * 256 + threadIdx.x;
  if (i >= O * Csub) return;
  int c = i / O, o = i - c * O;
  dst[(size_t)c * O + o] = src[(size_t)o * Ctot + cOff + c];
}

// ---------------- conv8: y8p[wc][b,o,h] = sum_{w in chunk, c} w8t[w,o,c] * h3T[b, idx[b,w,h], c]
#define C8P 260
#define Y8N (BATCH * 256 * 32)
__global__ __launch_bounds__(256) void conv8_kernel(
    const float* __restrict__ h3T, const float* __restrict__ w8t,
    const int* __restrict__ idxp, float* __restrict__ y8p)
{
  __shared__ float Wl[32][C8P];
  __shared__ float Gl[32][C8P];
  const int wc = blockIdx.x;       // 0..3 (w chunk of 64)
  const int o0 = blockIdx.y * 32;  // 8 o-tiles
  const int b  = blockIdx.z;
  const int t  = threadIdx.x;
  const int lo = t & 31;           // o lane
  const int hb = (t >> 5) * 4;     // h base (0,4,...,28)
  const int sr = t >> 3;           // staging row 0..31
  const int sc = (t & 7) * 32;     // staging col base
  float a0 = 0.f, a1 = 0.f, a2 = 0.f, a3 = 0.f;

  for (int w = wc * 64; w < wc * 64 + 64; ++w) {
    { // stage weights
      const float* src = w8t + ((size_t)w * 256 + o0 + sr) * 256 + sc;
      for (int j = 0; j < 32; j += 4)
        *(float4*)&Wl[sr][sc + j] = *(const float4*)&src[j];
    }
    { // stage gathered point features
      const int n = idxp[((size_t)b * 256 + w) * 32 + sr];
      const float* src = h3T + ((size_t)b * NPTS + n) * 256 + sc;
      for (int j = 0; j < 32; j += 4)
        *(float4*)&Gl[sr][sc + j] = *(const float4*)&src[j];
    }
    __syncthreads();
#pragma unroll 4
    for (int c = 0; c < 256; c += 4) {
      float4 wv = *(const float4*)&Wl[lo][c];
      float4 g0 = *(const float4*)&Gl[hb + 0][c];
      float4 g1 = *(const float4*)&Gl[hb + 1][c];
      float4 g2 = *(const float4*)&Gl[hb + 2][c];
      float4 g3 = *(const float4*)&Gl[hb + 3][c];
      a0 += wv.x * g0.x + wv.y * g0.y + wv.z * g0.z + wv.w * g0.w;
      a1 += wv.x * g1.x + wv.y * g1.y + wv.z * g1.z + wv.w * g1.w;
      a2 += wv.x * g2.x + wv.y * g2.y + wv.z * g2.z + wv.w * g2.w;
      a3 += wv.x * g3.x + wv.y * g3.y + wv.z * g3.z + wv.w * g3.w;
    }
    __syncthreads();
  }
  float* dst = &y8p[(size_t)wc * Y8N + ((size_t)b * 256 + o0 + lo) * 32 + hb];
  dst[0] = a0; dst[1] = a1; dst[2] = a2; dst[3] = a3;
}

// ---------------- y8[b,o,h] = b8[o] + sum_wc y8p[wc][b,o,h]  (fixed order, deterministic)
__global__ __launch_bounds__(256) void y8_reduce(const float* __restrict__ y8p,
                                                 const float* __restrict__ b8,
                                                 float* __restrict__ y8) {
  int i = blockIdx.x * 256 + threadIdx.x; // Y8N
  float s = b8[(i >> 5) & 255];
  s += y8p[i];
  s += y8p[Y8N + i];
  s += y8p[2 * Y8N + i];
  s += y8p[3 * Y8N + i];
  y8[i] = s;
}

// ---------------- conv9: y9[b,o] = b9[o] + sum_{i<8192} y8[b,i] * w9[o,i]
__global__ __launch_bounds__(256) void conv9_kernel(const float* __restrict__ y8,
                                                    const float* __restrict__ w9,
                                                    const float* __restrict__ b9,
                                                    float* __restrict__ y9) {
  const int o = blockIdx.x, b = blockIdx.y;
  const float* yb = y8 + (size_t)b * 8192;
  const float* wo = w9 + (size_t)o * 8192;
  float s = 0.f;
  for (int i = threadIdx.x * 4; i < 8192; i += 1024) {
    float4 v = *(const float4*)&yb[i];
    float4 u = *(const float4*)&wo[i];
    s += v.x * u.x + v.y * u.y + v.z * u.z + v.w * u.w;
  }
  for (int off = 32; off; off >>= 1) s += __shfl_down(s, off, 64);
  __shared__ float ls[4];
  const int wid = threadIdx.x >> 6;
  if ((threadIdx.x & 63) == 0) ls[wid] = s;
  __syncthreads();
  if (threadIdx.x == 0) y9[(size_t)b * 256 + o] = ls[0] + ls[1] + ls[2] + ls[3] + b9[o];
}

// ---------------- cvec[b,o] = sum_{c<256} w4[o,c] * y9[b,c]  (glob contribution to conv4)
__global__ __launch_bounds__(256) void cvec_kernel(const float* __restrict__ y9,
                                                   const float* __restrict__ w4,
                                                   float* __restrict__ cvec) {
  int tid = blockIdx.x * 256 + threadIdx.x; // 16*512
  if (tid >= BATCH * 512) return;
  const int b = tid >> 9, o = tid & 511;
  const float* row = w4 + (size_t)o * 320;
  const float* yb  = y9 + (size_t)b * 256;
  float s = 0.f;
  for (int c = 0; c < 256; c += 4) {
    float4 u = *(const float4*)&row[c];
    s += u.x * yb[c] + u.y * yb[c + 1] + u.z * yb[c + 2] + u.w * yb[c + 3];
  }
  cvec[(size_t)b * 512 + o] = s;
}

// ---------------- final tanh
__global__ __launch_bounds__(256) void tanh_out(const float* __restrict__ raw,
                                                float* __restrict__ out) {
  int i = blockIdx.x * 256 + threadIdx.x;
  if (i < BATCH * 3 * NPTS) out[i] = tanhf(raw[i]);
}

extern "C" void kernel_launch(void* const* d_in, const int* in_sizes, int n_in,
                              void* d_out, int out_size, void* d_ws, size_t ws_size,
                              hipStream_t stream) {
  (void)in_sizes; (void)n_in; (void)ws_size; (void)out_size;
  const float* x   = (const float*)d_in[0];
  const float* w1  = (const float*)d_in[1];
  const float* g1  = (const float*)d_in[3];
  const float* be1 = (const float*)d_in[4];
  const float* w2  = (const float*)d_in[5];
  const float* g2  = (const float*)d_in[7];
  const float* be2 = (const float*)d_in[8];
  const float* w3  = (const float*)d_in[9];
  const float* g3  = (const float*)d_in[11];
  const float* be3 = (const float*)d_in[12];
  const float* w4  = (const float*)d_in[13];
  const float* g4  = (const float*)d_in[15];
  const float* be4 = (const float*)d_in[16];
  const float* w5  = (const float*)d_in[17];
  const float* g5  = (const float*)d_in[19];
  const float* be5 = (const float*)d_in[20];
  const float* w6  = (const float*)d_in[21];
  const float* g6  = (const float*)d_in[23];
  const float* be6 = (const float*)d_in[24];
  const float* w7  = (const float*)d_in[25];
  const float* b7  = (const float*)d_in[26];
  const float* w8  = (const float*)d_in[27];
  const float* b8  = (const float*)d_in[28];
  const float* w9  = (const float*)d_in[29];
  const float* b9  = (const float*)d_in[30];

  char* ws = (char*)d_ws;
  size_t off = 0;
  auto alloc = [&](size_t bytes) -> void* {
    void* p = ws + off;
    off += (bytes + 255) & ~(size_t)255;
    return p;
  };
  // Big regions (Q2..Q4 contiguous: conv4 raw/h4 (128MB) overlays them after they die)
  float* Q1  = (float*)alloc((size_t)BATCH * 64  * NPTS * 4);  // h1 / later raw7
  float* Q2  = (float*)alloc((size_t)BATCH * 128 * NPTS * 4);  // h2 / later h4 base, h6
  float* Q3  = (float*)alloc((size_t)BATCH * 256 * NPTS * 4);  // h3
  float* Q4  = (float*)alloc((size_t)BATCH * 256 * NPTS * 4);  // h3T
  float* Q5  = (float*)alloc((size_t)BATCH * 256 * NPTS * 4);  // w8t (early) / h5 (late)
  int*   idx  = (int*)alloc((size_t)BATCH * 256 * 32 * 4);
  float* y8p  = (float*)alloc((size_t)4 * Y8N * 4);
  float* y8   = (float*)alloc((size_t)Y8N * 4);
  float* y9   = (float*)alloc((size_t)BATCH * 256 * 4);
  float* cvec = (float*)alloc((size_t)BATCH * 512 * 4);
  float* partials = (float*)alloc((size_t)2 * BATCH * 512 * 4);
  float* scale = (float*)alloc(512 * 4);
  float* shift = (float*)alloc(512 * 4);
  float* w1t  = (float*)alloc(4   * 64  * 4);
  float* w2t  = (float*)alloc(64  * 128 * 4);
  float* w3t  = (float*)alloc(128 * 256 * 4);
  float* w4bt = (float*)alloc(64  * 512 * 4);
  float* w5t  = (float*)alloc(512 * 256 * 4);
  float* w6t  = (float*)alloc(256 * 128 * 4);
  float* w7t  = (float*)alloc(128 * 3   * 4);
  float* w8t  = (float*)Q5;  // 67.1MB == Q5 size exactly, dead before h5 is written

  float* h4 = Q2;  // 128MB spans Q2+Q3+(part of)Q4 (167MB), all dead by conv4 time

  auto bn = [&](float* raw, int C, const float* g, const float* be, int relu) {
    bn_reduce<<<dim3(C, BATCH), 256, 0, stream>>>(raw, partials, C);
    bn_finalize<<<(C + 255) / 256, 256, 0, stream>>>(partials, g, be, scale, shift, C);
    size_t total4 = (size_t)BATCH * C * NPTS / 4;
    bn_apply<<<(unsigned)((total4 + 255) / 256), 256, 0, stream>>>(raw, scale, shift, C, relu);
  };

  // ---- weight preprocessing
  transpose_w<<<(4 * 64 + 255) / 256,   256, 0, stream>>>(w1, w1t, 64, 4, 0, 4);
  transpose_w<<<(64 * 128 + 255) / 256, 256, 0, stream>>>(w2, w2t, 128, 64, 0, 64);
  transpose_w<<<(128 * 256 + 255) / 256,256, 0, stream>>>(w3, w3t, 256, 128, 0, 128);
  transpose_w<<<(64 * 512 + 255) / 256, 256, 0, stream>>>(w4, w4bt, 512, 320, 256, 64);
  transpose_w<<<(512 * 256 + 255) / 256,256, 0, stream>>>(w5, w5t, 256, 512, 0, 512);
  transpose_w<<<(256 * 128 + 255) / 256,256, 0, stream>>>(w6, w6t, 128, 256, 0, 256);
  transpose_w<<<(128 * 3 + 255) / 256,  256, 0, stream>>>(w7, w7t, 3, 128, 0, 128);
  transpose_w8<<<dim3(1024, 4), 256, 0, stream>>>(w8, w8t);

  // ---- conv1 + bn + relu -> h1 (Q1)   [conv biases cancel in training-mode BN]
  conv_gemm<<<dim3(64, 1, BATCH), 256, 0, stream>>>(x, w1t, nullptr, nullptr, Q1, 4, 64);
  bn(Q1, 64, g1, be1, 1);
  // ---- conv2 + bn + relu -> h2 (Q2)
  conv_gemm<<<dim3(64, 2, BATCH), 256, 0, stream>>>(Q1, w2t, nullptr, nullptr, Q2, 64, 128);
  bn(Q2, 128, g2, be2, 1);
  // ---- conv3 + bn (no relu) -> h3 (Q3)
  conv_gemm<<<dim3(64, 4, BATCH), 256, 0, stream>>>(Q2, w3t, nullptr, nullptr, Q3, 128, 256);
  bn(Q3, 256, g3, be3, 0);

  // ---- softpool: top-32 indices, transpose h3 for coalesced gather
  topk_kernel<<<dim3(256, BATCH), 256, 0, stream>>>(Q3, idx);
  transpose_h3<<<dim3(NPTS / 32, 8, BATCH), 256, 0, stream>>>(Q3, Q4);

  // ---- conv8 (gathered) -> y8p -> y8 (deterministic), conv9 -> y9
  conv8_kernel<<<dim3(4, 8, BATCH), 256, 0, stream>>>(Q4, w8t, idx, y8p);
  y8_reduce<<<Y8N / 256, 256, 0, stream>>>(y8p, b8, y8);
  conv9_kernel<<<dim3(256, BATCH), 256, 0, stream>>>(y8, w9, b9, y9);

  // ---- conv4: glob part is constant over n -> cvec; pointfeat GEMM (K=64)
  cvec_kernel<<<(BATCH * 512 + 255) / 256, 256, 0, stream>>>(y9, w4, cvec);
  conv_gemm<<<dim3(64, 8, BATCH), 256, 0, stream>>>(Q1, w4bt, cvec, nullptr, h4, 64, 512);
  bn(h4, 512, g4, be4, 1);
  // ---- conv5 + bn + relu -> h5 (Q5, w8t is dead)
  conv_gemm<<<dim3(64, 4, BATCH), 256, 0, stream>>>(h4, w5t, nullptr, nullptr, Q5, 512, 256);
  bn(Q5, 256, g5, be5, 1);
  // ---- conv6 + bn + relu -> h6 (Q2 base, h4 is dead)
  conv_gemm<<<dim3(64, 2, BATCH), 256, 0, stream>>>(Q5, w6t, nullptr, nullptr, Q2, 256, 128);
  bn(Q2, 128, g6, be6, 1);
  // ---- conv7 (+b7) -> raw (Q1, h1 dead), tanh -> out
  conv_gemm<<<dim3(64, 1, BATCH), 256, 0, stream>>>(Q2, w7t, nullptr, b7, Q1, 128, 3);
  tanh_out<<<(BATCH * 3 * NPTS) / 256, 256, 0, stream>>>(Q1, (float*)d_out);
}

// Round 4
// 1386.334 us; speedup vs baseline: 1.2734x; 1.2734x over previous
//
#include <hip/hip_runtime.h>
#include <cstdint>
#include <cstddef>

#define NPTS 4096
#define BATCH 16

typedef unsigned int uint32;
typedef unsigned short ushort16_t;

typedef __attribute__((ext_vector_type(8))) short short8;
typedef __attribute__((ext_vector_type(16))) float float16;

__device__ __forceinline__ ushort16_t f2bf(float f) {
  uint32 u = __float_as_uint(f);
  u = (u + 0x7fffu + ((u >> 16) & 1u)) >> 16;
  return (ushort16_t)u;
}
__device__ __forceinline__ float bf2f(ushort16_t h) {
  return __uint_as_float(((uint32)h) << 16);
}

// ---------------- 1x1-conv GEMM with fused input-BN(+relu) and output-BN partial stats.
// out[b,o,n] = base(b,o) + sum_c wt[c,o] * f(act[b,c,n]),  f = relu(x*sc[c]+sh[c]) if inScale
// partials (if non-null): per-(b,o,ntile) sum and sumsq of the raw output (deterministic).
__global__ __launch_bounds__(256) void conv_gemm(
    const float* __restrict__ act, const float* __restrict__ wt,
    const float* __restrict__ rowbias, const float* __restrict__ obias,
    const float* __restrict__ inScale, const float* __restrict__ inShift,
    float* __restrict__ out, float* __restrict__ partials, int C, int O)
{
  __shared__ float As[16][68];
  __shared__ float Ws[16][68];
  __shared__ float redS[64][17];
  __shared__ float redQ[64][17];
  const int b  = blockIdx.z;
  const int o0 = blockIdx.y * 64;
  const int n0 = blockIdx.x * 64;
  const int t  = threadIdx.x;
  const int tx = t & 15, ty = t >> 4;
  float acc[4][4] = {};
  const float* actb = act + ((size_t)b * C) * NPTS;

  for (int k0 = 0; k0 < C; k0 += 16) {
    const int r  = ty;
    const int cs = tx * 4;
    const int k  = k0 + r;
    float4 av = make_float4(0.f, 0.f, 0.f, 0.f);
    if (k < C) {
      av = *(const float4*)(actb + (size_t)k * NPTS + n0 + cs);
      if (inScale) {
        const float scv = inScale[k], shv = inShift[k];
        av.x = fmaxf(fmaf(av.x, scv, shv), 0.f);
        av.y = fmaxf(fmaf(av.y, scv, shv), 0.f);
        av.z = fmaxf(fmaf(av.z, scv, shv), 0.f);
        av.w = fmaxf(fmaf(av.w, scv, shv), 0.f);
      }
    }
    *(float4*)&As[r][cs] = av;

    float4 wv = make_float4(0.f, 0.f, 0.f, 0.f);
    if (k < C) {
      const float* wp = wt + (size_t)k * O;
      const int o = o0 + cs;
      if (o + 3 < O) {
        wv = *(const float4*)&wp[o];
      } else {
        float tmp[4] = {0.f, 0.f, 0.f, 0.f};
        for (int j = 0; j < 4; ++j) if (o + j < O) tmp[j] = wp[o + j];
        wv = make_float4(tmp[0], tmp[1], tmp[2], tmp[3]);
      }
    }
    *(float4*)&Ws[r][cs] = wv;
    __syncthreads();

    const int kmax = (C - k0 < 16) ? (C - k0) : 16;
    for (int kk = 0; kk < kmax; ++kk) {
      float4 a = *(float4*)&As[kk][tx * 4];
      float4 w = *(float4*)&Ws[kk][ty * 4];
      acc[0][0] += w.x * a.x; acc[0][1] += w.x * a.y; acc[0][2] += w.x * a.z; acc[0][3] += w.x * a.w;
      acc[1][0] += w.y * a.x; acc[1][1] += w.y * a.y; acc[1][2] += w.y * a.z; acc[1][3] += w.y * a.w;
      acc[2][0] += w.z * a.x; acc[2][1] += w.z * a.y; acc[2][2] += w.z * a.z; acc[2][3] += w.z * a.w;
      acc[3][0] += w.w * a.x; acc[3][1] += w.w * a.y; acc[3][2] += w.w * a.z; acc[3][3] += w.w * a.w;
    }
    __syncthreads();
  }

  float s[4], q[4];
  for (int i = 0; i < 4; ++i) {
    const int o = o0 + ty * 4 + i;
    s[i] = 0.f; q[i] = 0.f;
    if (o >= O) continue;
    float base = 0.f;
    if (rowbias) base  = rowbias[(size_t)b * O + o];
    if (obias)   base += obias[o];
    float4 v = make_float4(acc[i][0] + base, acc[i][1] + base, acc[i][2] + base, acc[i][3] + base);
    *(float4*)&out[((size_t)b * O + o) * NPTS + n0 + tx * 4] = v;
    s[i] = v.x + v.y + v.z + v.w;
    q[i] = v.x * v.x + v.y * v.y + v.z * v.z + v.w * v.w;
  }

  if (partials) {
    for (int i = 0; i < 4; ++i) { redS[ty * 4 + i][tx] = s[i]; redQ[ty * 4 + i][tx] = q[i]; }
    __syncthreads();
    if (t < 64) {
      float a = 0.f;
      for (int j = 0; j < 16; ++j) a += redS[t][j];
      partials[((size_t)b * O + o0 + t) * 64 + blockIdx.x] = a;
    } else if (t < 128) {
      float a = 0.f;
      for (int j = 0; j < 16; ++j) a += redQ[t - 64][j];
      partials[(size_t)BATCH * O * 64 + ((size_t)b * O + o0 + t - 64) * 64 + blockIdx.x] = a;
    }
  }
}

// ---------------- BN finalize from conv partials (fixed order, deterministic)
__global__ __launch_bounds__(256) void bn_finalize(const float* __restrict__ ps,
                                                   const float* __restrict__ g, const float* __restrict__ be,
                                                   float* __restrict__ scale, float* __restrict__ shift, int O) {
  int c = blockIdx.x * 256 + threadIdx.x;
  if (c >= O) return;
  const float* p2 = ps + (size_t)BATCH * O * 64;
  float s = 0.f, q = 0.f;
  for (int b = 0; b < BATCH; ++b) {
    size_t base = ((size_t)b * O + c) * 64;
    for (int nt = 0; nt < 64; ++nt) { s += ps[base + nt]; q += p2[base + nt]; }
  }
  const float inv = 1.f / 65536.f;
  float m   = s * inv;
  float var = q * inv - m * m;
  float sc  = g[c] * rsqrtf(var + 1e-5f);
  scale[c] = sc;
  shift[c] = be[c] - m * sc;
}

// ---------------- top-32 per (b, sorting-channel) on RAW h3 (per-channel affine with
// scale=g*rsqrt(var)>0 is monotone -> identical indices). Lower index wins ties.
__global__ __launch_bounds__(256) void topk_kernel(const float* __restrict__ h3,
                                                   int* __restrict__ idxp) {
  __shared__ float vals[NPTS];
  __shared__ float wv[4];
  __shared__ int   wi[4];
  const int c = blockIdx.x, b = blockIdx.y;
  const float* src = h3 + ((size_t)b * 256 + c) * NPTS;
  const int t = threadIdx.x;
  for (int i = t; i < NPTS; i += 256) vals[i] = src[i];
  __syncthreads();
  int* dst = idxp + ((size_t)b * 256 + c) * 32;
  for (int r = 0; r < 32; ++r) {
    float bv = -INFINITY; int bi = NPTS;
    for (int i = t; i < NPTS; i += 256) {
      float v = vals[i];
      if (v > bv || (v == bv && i < bi)) { bv = v; bi = i; }
    }
    for (int off = 32; off; off >>= 1) {
      float ov = __shfl_down(bv, off, 64);
      int   oi = __shfl_down(bi, off, 64);
      if (ov > bv || (ov == bv && oi < bi)) { bv = ov; bi = oi; }
    }
    const int wid = t >> 6;
    if ((t & 63) == 0) { wv[wid] = bv; wi[wid] = bi; }
    __syncthreads();
    if (t == 0) {
      for (int k = 1; k < 4; ++k)
        if (wv[k] > bv || (wv[k] == bv && wi[k] < bi)) { bv = wv[k]; bi = wi[k]; }
      dst[r] = bi;
      vals[bi] = -INFINITY;
    }
    __syncthreads();
  }
}

// ---------------- transpose h3 (B,C,N) -> h3T (B,N,C), applying BN scale/shift (no relu)
__global__ __launch_bounds__(256) void transpose_h3(const float* __restrict__ h3,
                                                    float* __restrict__ h3T,
                                                    const float* __restrict__ sc,
                                                    const float* __restrict__ sh) {
  __shared__ float tile[32][33];
  const int b = blockIdx.z;
  const int n0 = blockIdx.x * 32, c0 = blockIdx.y * 32;
  const int tx = threadIdx.x & 31, ty = threadIdx.x >> 5;
  const float* src = h3 + (size_t)b * 256 * NPTS;
  for (int j = 0; j < 4; ++j)
    tile[ty + j * 8][tx] = src[(size_t)(c0 + ty + j * 8) * NPTS + n0 + tx];
  __syncthreads();
  float* dst = h3T + (size_t)b * NPTS * 256;
  const float scv = sc[c0 + tx], shv = sh[c0 + tx];
  for (int j = 0; j < 4; ++j)
    dst[(size_t)(n0 + ty + j * 8) * 256 + c0 + tx] = fmaf(tile[tx][ty + j * 8], scv, shv);
}

// ---------------- transpose w8 (o,c,w) -> w8t (w,o,c)  [65536 x 256 2D transpose, fp32]
__global__ __launch_bounds__(256) void transpose_w8(const float* __restrict__ w8,
                                                    float* __restrict__ w8t) {
  __shared__ float tile[64][65];
  const int m0 = blockIdx.x * 64, w0 = blockIdx.y * 64;
  const int tx = threadIdx.x & 63, ty = threadIdx.x >> 6;
  for (int j = 0; j < 16; ++j)
    tile[ty + j * 4][tx] = w8[(size_t)(m0 + ty + j * 4) * 256 + w0 + tx];
  __syncthreads();
  for (int j = 0; j < 16; ++j)
    w8t[(size_t)(w0 + ty + j * 4) * 65536 + m0 + tx] = tile[tx][ty + j * 4];
}

// ---------------- pack w8t (w,o,c) fp32 -> hi/lo bf16 in MFMA A-fragment order:
// index = ((((w*8 + mt)*16 + ks)*64 + lane)*8 + j); o = mt*32+(lane&31); c = ks*16+(lane>>5)*8+j
__global__ __launch_bounds__(256) void pack_w8(const float* __restrict__ w8t,
                                               ushort16_t* __restrict__ w8h,
                                               ushort16_t* __restrict__ w8l) {
  size_t i = (size_t)blockIdx.x * 256 + threadIdx.x;  // 16,777,216 total
  int j  = (int)(i & 7);
  int lj = (int)((i >> 3) & 63);
  int ks = (int)((i >> 9) & 15);
  int mt = (int)((i >> 13) & 7);
  int w  = (int)(i >> 16);
  int o  = mt * 32 + (lj & 31);
  int c  = ks * 16 + (lj >> 5) * 8 + j;
  float v = w8t[((size_t)w << 16) + (size_t)o * 256 + c];
  ushort16_t h = f2bf(v);
  w8h[i] = h;
  w8l[i] = f2bf(v - bf2f(h));
}

// ---------------- conv8 via MFMA 32x32x16 bf16: per (b,w): D[o,h] = sum_c W[o,c]*Gn[c,h]
// W = Whi + Wlo (split bf16, register-resident A-frags); Gn single-bf16, LDS B-frag order,
// double-buffered over b. Partials per w-group; deterministic.
#define Y8N (BATCH * 256 * 32)
__global__ __launch_bounds__(256, 1) void conv8_mfma(
    const float* __restrict__ h3T, const ushort16_t* __restrict__ w8h,
    const ushort16_t* __restrict__ w8l, const int* __restrict__ idxp,
    float* __restrict__ y8p)
{
  __shared__ ushort16_t G[2][8192];   // 16 KB per buffer, B-frag order
  const int wg = blockIdx.x;          // 32 groups of 8 w
  const int oq = blockIdx.y;          // 0..1 -> 128 o
  const int bg = blockIdx.z;          // 0..3 -> 4 b
  const int t  = threadIdx.x;
  const int l  = t & 63, wv = t >> 6;
  const int mt = oq * 4 + wv;         // global m-tile (32 o each)

  float16 accH[4], accL[4];
  for (int i = 0; i < 4; ++i)
    for (int r = 0; r < 16; ++r) { accH[i][r] = 0.f; accL[i][r] = 0.f; }

  short8 ah[16], al[16];
  const int hrow  = t >> 3;           // 0..31
  const int cbase = (t & 7) * 32;
  float4 g4[8];

  auto issueG = [&](int step) {
    int wi = step >> 2, bi = step & 3;
    int w = wg * 8 + wi;
    int b = bg * 4 + bi;
    int n = idxp[((size_t)b * 256 + w) * 32 + hrow];
    const float* src = h3T + ((size_t)b * NPTS + n) * 256 + cbase;
#pragma unroll
    for (int j = 0; j < 8; ++j) g4[j] = *(const float4*)&src[j * 4];
  };
  auto writeG = [&](int buf) {
#pragma unroll
    for (int a = 0; a < 4; ++a) {
      int c8 = (cbase >> 3) + a;
      int ks = c8 >> 1;
      int lp = hrow + (c8 & 1) * 32;
      float4 v0 = g4[a * 2], v1 = g4[a * 2 + 1];
      uint32 u0 = (uint32)f2bf(v0.x) | ((uint32)f2bf(v0.y) << 16);
      uint32 u1 = (uint32)f2bf(v0.z) | ((uint32)f2bf(v0.w) << 16);
      uint32 u2 = (uint32)f2bf(v1.x) | ((uint32)f2bf(v1.y) << 16);
      uint32 u3 = (uint32)f2bf(v1.z) | ((uint32)f2bf(v1.w) << 16);
      *(uint4*)&G[buf][((size_t)ks * 64 + lp) * 8] = make_uint4(u0, u1, u2, u3);
    }
  };

  issueG(0); writeG(0);
  __syncthreads();

  for (int wi = 0; wi < 8; ++wi) {
    const int w = wg * 8 + wi;
    {
      const size_t base = (((size_t)w * 8 + mt) * 16) * 512 + (size_t)l * 8;
#pragma unroll
      for (int ks = 0; ks < 16; ++ks) {
        ah[ks] = *(const short8*)(w8h + base + ks * 512);
        al[ks] = *(const short8*)(w8l + base + ks * 512);
      }
    }
#pragma unroll
    for (int bi = 0; bi < 4; ++bi) {
      const int step = wi * 4 + bi;
      const int cur = bi & 1;          // wi*4 is even
      if (step < 31) issueG(step + 1);
      const ushort16_t* Gc = G[cur];
#pragma unroll
      for (int ks = 0; ks < 16; ++ks) {
        short8 bf = *(const short8*)&Gc[((size_t)ks * 64 + l) * 8];
        accH[bi] = __builtin_amdgcn_mfma_f32_32x32x16_bf16(ah[ks], bf, accH[bi], 0, 0, 0);
        accL[bi] = __builtin_amdgcn_mfma_f32_32x32x16_bf16(al[ks], bf, accL[bi], 0, 0, 0);
      }
      if (step < 31) writeG(1 - cur);
      __syncthreads();
    }
  }

  // epilogue: D row = (r&3) + 8*(r>>2) + 4*(lane>>5), col = lane&31  [verified mapping]
  const int h = l & 31;
  const int rbase = oq * 128 + wv * 32 + 4 * (l >> 5);
#pragma unroll
  for (int bi = 0; bi < 4; ++bi) {
    int b = bg * 4 + bi;
    float* dst = y8p + ((size_t)(wg * BATCH + b) * 256) * 32;
#pragma unroll
    for (int r = 0; r < 16; ++r) {
      int o = rbase + (r & 3) + 8 * (r >> 2);
      dst[(size_t)o * 32 + h] = accH[bi][r] + accL[bi][r];
    }
  }
}

// ---------------- y8[b,o,h] = b8[o] + sum_{wg<32} y8p[wg][b,o,h]  (fixed order)
__global__ __launch_bounds__(256) void y8_reduce(const float* __restrict__ y8p,
                                                 const float* __restrict__ b8,
                                                 float* __restrict__ y8) {
  int i = blockIdx.x * 256 + threadIdx.x;
  float s = b8[(i >> 5) & 255];
#pragma unroll
  for (int p = 0; p < 32; ++p) s += y8p[(size_t)p * Y8N + i];
  y8[i] = s;
}

// ---------------- conv9: y9[b,o] = b9[o] + sum_{i<8192} y8[b,i] * w9[o,i]
__global__ __launch_bounds__(256) void conv9_kernel(const float* __restrict__ y8,
                                                    const float* __restrict__ w9,
                                                    const float* __restrict__ b9,
                                                    float* __restrict__ y9) {
  const int o = blockIdx.x, b = blockIdx.y;
  const float* yb = y8 + (size_t)b * 8192;
  const float* wo = w9 + (size_t)o * 8192;
  float s = 0.f;
  for (int i = threadIdx.x * 4; i < 8192; i += 1024) {
    float4 v = *(const float4*)&yb[i];
    float4 u = *(const float4*)&wo[i];
    s += v.x * u.x + v.y * u.y + v.z * u.z + v.w * u.w;
  }
  for (int off = 32; off; off >>= 1) s += __shfl_down(s, off, 64);
  __shared__ float ls[4];
  const int wid = threadIdx.x >> 6;
  if ((threadIdx.x & 63) == 0) ls[wid] = s;
  __syncthreads();
  if (threadIdx.x == 0) y9[(size_t)b * 256 + o] = ls[0] + ls[1] + ls[2] + ls[3] + b9[o];
}

// ---------------- cvec[b,o] = sum_{c<256} w4[o,c] * y9[b,c]
__global__ __launch_bounds__(256) void cvec_kernel(const float* __restrict__ y9,
                                                   const float* __restrict__ w4,
                                                   float* __restrict__ cvec) {
  int tid = blockIdx.x * 256 + threadIdx.x;
  if (tid >= BATCH * 512) return;
  const int b = tid >> 9, o = tid & 511;
  const float* row = w4 + (size_t)o * 320;
  const float* yb  = y9 + (size_t)b * 256;
  float s = 0.f;
  for (int c = 0; c < 256; c += 4) {
    float4 u = *(const float4*)&row[c];
    s += u.x * yb[c] + u.y * yb[c + 1] + u.z * yb[c + 2] + u.w * yb[c + 3];
  }
  cvec[(size_t)b * 512 + o] = s;
}

// ---------------- small weight transpose: dst(Csub,O) <- src(O,Ctot) cols [cOff, cOff+Csub)
__global__ __launch_bounds__(256) void transpose_w(const float* __restrict__ src,
                                                   float* __restrict__ dst,
                                                   int O, int Ctot, int cOff, int Csub) {
  int i = blockIdx.x * 256 + threadIdx.x;
  if (i >= O * Csub) return;
  int c = i / O, o = i - c * O;
  dst[(size_t)c * O + o] = src[(size_t)o * Ctot + cOff + c];
}

// ---------------- final tanh
__global__ __launch_bounds__(256) void tanh_out(const float* __restrict__ raw,
                                                float* __restrict__ out) {
  int i = blockIdx.x * 256 + threadIdx.x;
  if (i < BATCH * 3 * NPTS) out[i] = tanhf(raw[i]);
}

extern "C" void kernel_launch(void* const* d_in, const int* in_sizes, int n_in,
                              void* d_out, int out_size, void* d_ws, size_t ws_size,
                              hipStream_t stream) {
  (void)in_sizes; (void)n_in; (void)ws_size; (void)out_size;
  const float* x   = (const float*)d_in[0];
  const float* w1  = (const float*)d_in[1];
  const float* g1  = (const float*)d_in[3];
  const float* be1 = (const float*)d_in[4];
  const float* w2  = (const float*)d_in[5];
  const float* g2  = (const float*)d_in[7];
  const float* be2 = (const float*)d_in[8];
  const float* w3  = (const float*)d_in[9];
  const float* g3  = (const float*)d_in[11];
  const float* be3 = (const float*)d_in[12];
  const float* w4  = (const float*)d_in[13];
  const float* g4  = (const float*)d_in[15];
  const float* be4 = (const float*)d_in[16];
  const float* w5  = (const float*)d_in[17];
  const float* g5  = (const float*)d_in[19];
  const float* be5 = (const float*)d_in[20];
  const float* w6  = (const float*)d_in[21];
  const float* g6  = (const float*)d_in[23];
  const float* be6 = (const float*)d_in[24];
  const float* w7  = (const float*)d_in[25];
  const float* b7  = (const float*)d_in[26];
  const float* w8  = (const float*)d_in[27];
  const float* b8  = (const float*)d_in[28];
  const float* w9  = (const float*)d_in[29];
  const float* b9  = (const float*)d_in[30];

  char* ws = (char*)d_ws;
  size_t off = 0;
  auto alloc = [&](size_t bytes) -> void* {
    void* p = ws + off;
    off += (bytes + 255) & ~(size_t)255;
    return p;
  };
  float* Q1  = (float*)alloc((size_t)BATCH * 64  * NPTS * 4);  // h1 / later raw7
  float* Q2  = (float*)alloc((size_t)BATCH * 128 * NPTS * 4);  // h2 / y8p / h4 base / h6
  float* Q3  = (float*)alloc((size_t)BATCH * 256 * NPTS * 4);  // h3 (raw)
  float* Q4  = (float*)alloc((size_t)BATCH * 256 * NPTS * 4);  // w8t (early) / h3T (normalized)
  float* Q5  = (float*)alloc((size_t)BATCH * 256 * NPTS * 4);  // w8h+w8l (early) / h5 (late)
  int*   idx  = (int*)alloc((size_t)BATCH * 256 * 32 * 4);
  float* y8   = (float*)alloc((size_t)Y8N * 4);
  float* y9   = (float*)alloc((size_t)BATCH * 256 * 4);
  float* cvec = (float*)alloc((size_t)BATCH * 512 * 4);
  float* ps   = (float*)alloc((size_t)2 * BATCH * 512 * 64 * 4);  // BN partials (max O=512)
  float* scb  = (float*)alloc((size_t)6 * 1024 * 4);              // 6 layers x (scale|shift)
  float* w1t  = (float*)alloc(4   * 64  * 4);
  float* w2t  = (float*)alloc(64  * 128 * 4);
  float* w3t  = (float*)alloc(128 * 256 * 4);
  float* w4bt = (float*)alloc(64  * 512 * 4);
  float* w5t  = (float*)alloc(512 * 256 * 4);
  float* w6t  = (float*)alloc(256 * 128 * 4);
  float* w7t  = (float*)alloc(128 * 3   * 4);

  float*      w8t = Q4;                                   // 67.1MB fp32, dead before h3T
  ushort16_t* w8h = (ushort16_t*)Q5;                      // 33.5MB
  ushort16_t* w8l = (ushort16_t*)Q5 + (size_t)16777216;   // 33.5MB; both dead before h5
  float*      y8p = Q2;                                   // 16.8MB <= 33.5MB, dead before h4
  float*      h4  = Q2;                                   // 134MB spans Q2..Q4-head (all dead then)

  float* sc[6]; float* sh[6];
  for (int i = 0; i < 6; ++i) { sc[i] = scb + i * 1024; sh[i] = scb + i * 1024 + 512; }

  // ---- weight preprocessing
  transpose_w<<<(4 * 64 + 255) / 256,   256, 0, stream>>>(w1, w1t, 64, 4, 0, 4);
  transpose_w<<<(64 * 128 + 255) / 256, 256, 0, stream>>>(w2, w2t, 128, 64, 0, 64);
  transpose_w<<<(128 * 256 + 255) / 256,256, 0, stream>>>(w3, w3t, 256, 128, 0, 128);
  transpose_w<<<(64 * 512 + 255) / 256, 256, 0, stream>>>(w4, w4bt, 512, 320, 256, 64);
  transpose_w<<<(512 * 256 + 255) / 256,256, 0, stream>>>(w5, w5t, 256, 512, 0, 512);
  transpose_w<<<(256 * 128 + 255) / 256,256, 0, stream>>>(w6, w6t, 128, 256, 0, 256);
  transpose_w<<<(128 * 3 + 255) / 256,  256, 0, stream>>>(w7, w7t, 3, 128, 0, 128);
  transpose_w8<<<dim3(1024, 4), 256, 0, stream>>>(w8, w8t);
  pack_w8<<<65536, 256, 0, stream>>>(w8t, w8h, w8l);

  // ---- conv1 (raw out + stats) ; BN fused downstream
  conv_gemm<<<dim3(64, 1, BATCH), 256, 0, stream>>>(x, w1t, nullptr, nullptr, nullptr, nullptr, Q1, ps, 4, 64);
  bn_finalize<<<1, 256, 0, stream>>>(ps, g1, be1, sc[0], sh[0], 64);
  // ---- conv2
  conv_gemm<<<dim3(64, 2, BATCH), 256, 0, stream>>>(Q1, w2t, nullptr, nullptr, sc[0], sh[0], Q2, ps, 64, 128);
  bn_finalize<<<1, 256, 0, stream>>>(ps, g2, be2, sc[1], sh[1], 128);
  // ---- conv3 (raw h3; topk is monotone-invariant)
  conv_gemm<<<dim3(64, 4, BATCH), 256, 0, stream>>>(Q2, w3t, nullptr, nullptr, sc[1], sh[1], Q3, ps, 128, 256);
  bn_finalize<<<1, 256, 0, stream>>>(ps, g3, be3, sc[2], sh[2], 256);

  // ---- softpool: top-32 on raw h3; transpose applies BN -> normalized h3T
  topk_kernel<<<dim3(256, BATCH), 256, 0, stream>>>(Q3, idx);
  transpose_h3<<<dim3(NPTS / 32, 8, BATCH), 256, 0, stream>>>(Q3, Q4, sc[2], sh[2]);

  // ---- conv8 (MFMA) -> y8p -> y8, conv9 -> y9
  conv8_mfma<<<dim3(32, 2, 4), 256, 0, stream>>>(Q4, w8h, w8l, idx, y8p);
  y8_reduce<<<Y8N / 256, 256, 0, stream>>>(y8p, b8, y8);
  conv9_kernel<<<dim3(256, BATCH), 256, 0, stream>>>(y8, w9, b9, y9);

  // ---- conv4: glob contribution as rowbias; pointfeat GEMM on raw h1 (fused BN1+relu)
  cvec_kernel<<<(BATCH * 512 + 255) / 256, 256, 0, stream>>>(y9, w4, cvec);
  conv_gemm<<<dim3(64, 8, BATCH), 256, 0, stream>>>(Q1, w4bt, cvec, nullptr, sc[0], sh[0], h4, ps, 64, 512);
  bn_finalize<<<2, 256, 0, stream>>>(ps, g4, be4, sc[3], sh[3], 512);
  // ---- conv5
  conv_gemm<<<dim3(64, 4, BATCH), 256, 0, stream>>>(h4, w5t, nullptr, nullptr, sc[3], sh[3], Q5, ps, 512, 256);
  bn_finalize<<<1, 256, 0, stream>>>(ps, g5, be5, sc[4], sh[4], 256);
  // ---- conv6 (h4 dead; writes Q2)
  conv_gemm<<<dim3(64, 2, BATCH), 256, 0, stream>>>(Q5, w6t, nullptr, nullptr, sc[4], sh[4], Q2, ps, 256, 128);
  bn_finalize<<<1, 256, 0, stream>>>(ps, g6, be6, sc[5], sh[5], 128);
  // ---- conv7 (+b7, fused BN6+relu input) -> raw (Q1), tanh -> out
  conv_gemm<<<dim3(64, 1, BATCH), 256, 0, stream>>>(Q2, w7t, nullptr, b7, sc[5], sh[5], Q1, nullptr, 128, 3);
  tanh_out<<<(BATCH * 3 * NPTS) / 256, 256, 0, stream>>>(Q1, (float*)d_out);
}